// Round 2
// baseline (2148.028 us; speedup 1.0000x reference)
//
#include <hip/hip_runtime.h>
#include <hip/hip_cooperative_groups.h>
#include <hip/hip_bf16.h>
#include <math.h>

namespace cg = cooperative_groups;

#define BATCH 8192
#define DDIM 256
#define HDIM 266
#define NPAD 320
#define TSTEPS 20
#define BN_EPS 1e-5f
#define LSTR 72         // LDS row stride in shorts (144 B; even bank spread for b128)

typedef __attribute__((ext_vector_type(8))) short short8;   // 8 bf16
typedef __attribute__((ext_vector_type(4))) float f32x4;

__device__ __forceinline__ short f2bf(float f) {
    __hip_bfloat16 h = __float2bfloat16(f);
    return *reinterpret_cast<short*>(&h);
}
__device__ __forceinline__ float bf2f(short s) {
    union { unsigned u; float f; } v;
    v.u = ((unsigned)(unsigned short)s) << 16;
    return v.f;
}

// ---------------------------------------------------------------------------
// prep: pad+convert all weights (bf16) / biases (fp32); zero stats region.
// ---------------------------------------------------------------------------
#define SZ_W1B (20L * 320 * 256)
#define SZ_W2B (20L * 320 * 320)
#define SZ_W3B (20L * 256 * 320)
#define SZ_VW1 (320L * 256)
#define SZ_VW2 (320L * 320)
#define SZ_B1P (20L * 320)
#define SZ_B2P (20L * 320)
#define ZCOUNT (4L * 21 * NPAD + 2)
#define PREP_TOTAL (SZ_W1B + SZ_W2B + SZ_W3B + SZ_VW1 + SZ_VW2 + SZ_B1P + SZ_B2P + 3 * 320 + ZCOUNT)

__global__ __launch_bounds__(256)
void prep_k(short* __restrict__ W1b, const float* __restrict__ W1,
            short* __restrict__ W2b, const float* __restrict__ W2,
            short* __restrict__ W3b, const float* __restrict__ W3,
            short* __restrict__ vW1b, const float* __restrict__ vW1,
            short* __restrict__ vW2b, const float* __restrict__ vW2,
            float* __restrict__ b1p, const float* __restrict__ b1,
            float* __restrict__ b2p, const float* __restrict__ b2,
            float* __restrict__ vb1p, const float* __restrict__ vb1,
            float* __restrict__ vb2p, const float* __restrict__ vb2,
            float* __restrict__ vW3p, const float* __restrict__ vW3,
            float* __restrict__ zbase)
{
    long idx = (long)blockIdx.x * 256 + threadIdx.x;
    if (idx < SZ_W1B) {  // [20][320][256], src [20][266][256]
        long k = idx % 256, r = (idx / 256) % 320, t = idx / (256L * 320);
        float v = (r < HDIM) ? W1[((size_t)t * HDIM + r) * 256 + k] : 0.0f;
        W1b[idx] = f2bf(v); return;
    }
    idx -= SZ_W1B;
    if (idx < SZ_W2B) {  // [20][320][320], src [20][266][266]
        long k = idx % 320, r = (idx / 320) % 320, t = idx / (320L * 320);
        float v = (r < HDIM && k < HDIM) ? W2[((size_t)t * HDIM + r) * HDIM + k] : 0.0f;
        W2b[idx] = f2bf(v); return;
    }
    idx -= SZ_W2B;
    if (idx < SZ_W3B) {  // [20][256][320], src [20][256][266]
        long k = idx % 320, r = (idx / 320) % 256, t = idx / (320L * 256);
        float v = (k < HDIM) ? W3[((size_t)t * 256 + r) * HDIM + k] : 0.0f;
        W3b[idx] = f2bf(v); return;
    }
    idx -= SZ_W3B;
    if (idx < SZ_VW1) {  // [320][256], src [266][256]
        long k = idx % 256, r = idx / 256;
        float v = (r < HDIM) ? vW1[(size_t)r * 256 + k] : 0.0f;
        vW1b[idx] = f2bf(v); return;
    }
    idx -= SZ_VW1;
    if (idx < SZ_VW2) {  // [320][320], src [266][266]
        long k = idx % 320, r = idx / 320;
        float v = (r < HDIM && k < HDIM) ? vW2[(size_t)r * HDIM + k] : 0.0f;
        vW2b[idx] = f2bf(v); return;
    }
    idx -= SZ_VW2;
    if (idx < SZ_B1P) { long n = idx % 320, t = idx / 320;
        b1p[idx] = (n < HDIM) ? b1[(size_t)t * HDIM + n] : 0.0f; return; }
    idx -= SZ_B1P;
    if (idx < SZ_B2P) { long n = idx % 320, t = idx / 320;
        b2p[idx] = (n < HDIM) ? b2[(size_t)t * HDIM + n] : 0.0f; return; }
    idx -= SZ_B2P;
    if (idx < 320) { vb1p[idx] = (idx < HDIM) ? vb1[idx] : 0.0f; return; }
    idx -= 320;
    if (idx < 320) { vb2p[idx] = (idx < HDIM) ? vb2[idx] : 0.0f; return; }
    idx -= 320;
    if (idx < 320) { vW3p[idx] = (idx < HDIM) ? vW3[idx] : 0.0f; return; }
    idx -= 320;
    if (idx < ZCOUNT) { zbase[idx] = 0.0f; return; }
}

// ---------------------------------------------------------------------------
// Persistent-kernel device helpers
// ---------------------------------------------------------------------------
__device__ __forceinline__ void bn_coeff(const float* __restrict__ cs,
                                         const float* __restrict__ cq,
                                         const float* __restrict__ g,
                                         const float* __restrict__ be,
                                         float* sS, float* sT, int tid)
{
    for (int k = tid; k < NPAD; k += 512) {
        float s = 0.0f, t = 0.0f;
        if (k < HDIM) {
            float mn = cs[k] * (1.0f / BATCH);
            float vr = cq[k] * (1.0f / BATCH) - mn * mn;
            float rs = rsqrtf(fmaxf(vr, 0.0f) + BN_EPS);
            s = g[k] * rs;
            t = be[k] - mn * s;
        }
        sS[k] = s; sT[k] = t;
    }
}

template<int NJ>
__device__ __forceinline__ void preload_w(const short* __restrict__ Wt, int KLEN,
                                          short8* rW, int tid)
{
    #pragma unroll
    for (int i = 0; i < NJ; ++i) {
        int s = tid + 512 * i;
        rW[i] = *(const short8*)(Wt + (size_t)(s >> 3) * KLEN + ((s & 7) * 8));
    }
}

// One GEMM phase: out 32 x (NJ*64), K = NKT*64.  A is chunk-major LDS
// ([chunk][32][LSTR]); if BN, A is re-normalized through As1 per chunk.
// rW must hold the chunk-0 weight tile (preloaded, possibly before grid.sync).
template<int NKT, int NJ, bool BN>
__device__ __forceinline__ void gemm_phase(
    const short* __restrict__ Wt, const short* Asrc, short* As1, short* Bs,
    const float* sS, const float* sT, f32x4* acc, short8* rW, int tid)
{
    const int lane = tid & 63, q = lane >> 4, m = lane & 15;
    const int w = tid >> 6, rh = w >> 2, ch = w & 3;
    const int srowA = tid >> 3, kqA = (tid & 7) * 8;
    const int KLEN = NKT * 64;

    #pragma unroll
    for (int kt = 0; kt < NKT; ++kt) {
        if (BN) {
            if (tid < 256) {
                short8 v = *(const short8*)&Asrc[(kt * 32 + srowA) * LSTR + kqA];
                short8 ta;
                #pragma unroll
                for (int j = 0; j < 8; ++j) {
                    int k = kt * 64 + kqA + j;
                    float f = bf2f(v[j]);
                    f = fmaxf(f * sS[k] + sT[k], 0.0f);
                    ta[j] = f2bf(f);
                }
                *(short8*)&As1[srowA * LSTR + kqA] = ta;
            }
        }
        #pragma unroll
        for (int i = 0; i < NJ; ++i) {
            int s = tid + 512 * i;
            *(short8*)&Bs[(s >> 3) * LSTR + (s & 7) * 8] = rW[i];
        }
        __syncthreads();
        if (kt < NKT - 1) {
            #pragma unroll
            for (int i = 0; i < NJ; ++i) {
                int s = tid + 512 * i;
                rW[i] = *(const short8*)(Wt + (size_t)(s >> 3) * KLEN
                                         + (kt + 1) * 64 + ((s & 7) * 8));
            }
        }
        const short* ab = BN ? As1 : (Asrc + kt * 32 * LSTR);
        #pragma unroll
        for (int kk = 0; kk < 2; ++kk) {
            short8 fa = *(const short8*)&ab[(rh * 16 + m) * LSTR + kk * 32 + q * 8];
            #pragma unroll
            for (int j = 0; j < NJ; ++j) {
                short8 fb = *(const short8*)&Bs[(ch * (NJ * 16) + j * 16 + m) * LSTR
                                                + kk * 32 + q * 8];
                acc[j] = __builtin_amdgcn_mfma_f32_16x16x32_bf16(fa, fb, acc[j], 0, 0, 0);
            }
        }
        __syncthreads();
    }
}

// Epilogue for 320-wide phases: bias-add, store raw pre-BN h (chunk-major LDS),
// column sum/sumsq partials -> global atomics (cols < HDIM).
__device__ __forceinline__ void epi_store_stats(
    const f32x4* acc, const float* __restrict__ bias, short* dst,
    float* redS, float* redQ, float* __restrict__ csum, float* __restrict__ csq,
    int tid)
{
    const int lane = tid & 63, q = lane >> 4, m = lane & 15;
    const int w = tid >> 6, rh = w >> 2, ch = w & 3;
    float csv[5], cqv[5];
    #pragma unroll
    for (int j = 0; j < 5; ++j) {
        const int col = ch * 80 + j * 16 + m;
        const float bv = bias[col];
        float s = 0.0f, sq = 0.0f;
        #pragma unroll
        for (int r = 0; r < 4; ++r) {
            float v = acc[j][r] + bv;
            int row = rh * 16 + q * 4 + r;
            dst[((col >> 6) * 32 + row) * LSTR + (col & 63)] = f2bf(v);
            s += v; sq += v * v;
        }
        csv[j] = s; cqv[j] = sq;
    }
    #pragma unroll
    for (int j = 0; j < 5; ++j) {
        csv[j] += __shfl_xor(csv[j], 16); csv[j] += __shfl_xor(csv[j], 32);
        cqv[j] += __shfl_xor(cqv[j], 16); cqv[j] += __shfl_xor(cqv[j], 32);
    }
    if (q == 0) {
        #pragma unroll
        for (int j = 0; j < 5; ++j) {
            int col = ch * 80 + j * 16 + m;
            redS[rh * NPAD + col] = csv[j];
            redQ[rh * NPAD + col] = cqv[j];
        }
    }
    __syncthreads();
    if (tid < HDIM) {
        atomicAdd(&csum[tid], redS[tid] + redS[NPAD + tid]);
        atomicAdd(&csq[tid],  redQ[tid] + redQ[NPAD + tid]);
    }
}

struct PArgs {
    const float* x; const float* xi; const float* tg;
    const short* W1b; const short* W2b; const short* W3b;
    const short* vW1b; const short* vW2b;
    const float* b1p; const float* b2p; const float* b3;
    const float* vb1p; const float* vb2p; const float* vW3p; const float* vb3;
    const float* g1; const float* be1; const float* g2; const float* be2;
    const float* vg1; const float* vbe1; const float* vg2; const float* vbe2;
    const float* vg3; const float* vbe3;
    float* csA; float* cqA; float* csB; float* cqB;
    float* s3; float* q3;
    float* out; float* xout;
};

// ---------------------------------------------------------------------------
// Persistent kernel: 256 blocks x 512 threads, each block owns 32 rows for the
// whole v-net + 20-step scan. xt/h1/h2 live in LDS; only weights, stats, xi
// touch global. Grid-wide sync only at the two BN-stat barriers per step.
// ---------------------------------------------------------------------------
__global__ __launch_bounds__(512)
void persist_k(PArgs p)
{
    cg::grid_group grid = cg::this_grid();

    __shared__ __align__(16) short xbuf[128 * LSTR];    // xt  [4 chunks][32][LSTR]
    __shared__ __align__(16) short h1buf[160 * LSTR];   // h1  [5][32][LSTR] (pre-BN)
    __shared__ __align__(16) short h2buf[160 * LSTR];   // h2  [5][32][LSTR] (pre-BN)
    __shared__ __align__(16) short Bs[320 * LSTR];      // weight K-chunk
    __shared__ __align__(16) short As1[32 * LSTR];      // BN-staged A chunk
    __shared__ float sS[NPAD], sT[NPAD];
    __shared__ float redS[2 * NPAD], redQ[2 * NPAD];
    __shared__ float redF[128], redD[128];
    __shared__ float pre3L[32], vacc[32];

    const int tid = threadIdx.x;
    const int row0 = blockIdx.x * 32;
    const int lane = tid & 63, w = tid >> 6, q = lane >> 4, m = lane & 15;
    const int rh = w >> 2, ch = w & 3;

    // stage x -> xbuf (bf16, chunk-major); init per-row v accumulator
    for (int i2 = tid; i2 < 32 * 256; i2 += 512) {
        int row = i2 >> 8, col = i2 & 255;
        xbuf[((col >> 6) * 32 + row) * LSTR + (col & 63)] =
            f2bf(p.x[(size_t)(row0 + row) * DDIM + col]);
    }
    if (tid < 32) vacc[tid] = 0.0f;

    short8 rW[5];
    f32x4 acc[5];

    // ---- v-net layer 1: hv1 = x @ vW1^T ----
    preload_w<5>(p.vW1b, DDIM, rW, tid);
    #pragma unroll
    for (int j = 0; j < 5; ++j) acc[j] = (f32x4){0.f, 0.f, 0.f, 0.f};
    __syncthreads();
    gemm_phase<4, 5, false>(p.vW1b, xbuf, As1, Bs, sS, sT, acc, rW, tid);
    epi_store_stats(acc, p.vb1p, h1buf, redS, redQ,
                    p.csA + 20 * NPAD, p.cqA + 20 * NPAD, tid);
    preload_w<5>(p.vW2b, NPAD, rW, tid);
    grid.sync();

    // ---- v-net layer 2: hv2 = bnrelu(hv1) @ vW2^T ----
    bn_coeff(p.csA + 20 * NPAD, p.cqA + 20 * NPAD, p.vg1, p.vbe1, sS, sT, tid);
    #pragma unroll
    for (int j = 0; j < 5; ++j) acc[j] = (f32x4){0.f, 0.f, 0.f, 0.f};
    __syncthreads();
    gemm_phase<5, 5, true>(p.vW2b, h1buf, As1, Bs, sS, sT, acc, rW, tid);
    epi_store_stats(acc, p.vb2p, h2buf, redS, redQ,
                    p.csB + 20 * NPAD, p.cqB + 20 * NPAD, tid);
    grid.sync();

    // ---- v-net layer 3: pre3 = bnrelu(hv2) . vW3 (row dot, block-local) ----
    bn_coeff(p.csB + 20 * NPAD, p.cqB + 20 * NPAD, p.vg2, p.vbe2, sS, sT, tid);
    __syncthreads();
    {
        const int wv = tid >> 6, ln = tid & 63;
        float ps = 0.0f, pq = 0.0f;
        #pragma unroll
        for (int r4 = 0; r4 < 4; ++r4) {
            int row = wv * 4 + r4;
            float sum = 0.0f;
            #pragma unroll
            for (int c = 0; c < 5; ++c) {
                int k = c * 64 + ln;
                float v = fmaxf(bf2f(h2buf[(c * 32 + row) * LSTR + ln]) * sS[k] + sT[k], 0.0f);
                sum += v * p.vW3p[k];
            }
            sum += __shfl_xor(sum, 1);  sum += __shfl_xor(sum, 2);
            sum += __shfl_xor(sum, 4);  sum += __shfl_xor(sum, 8);
            sum += __shfl_xor(sum, 16); sum += __shfl_xor(sum, 32);
            if (ln == 0) {
                float pv = sum + p.vb3[0];
                pre3L[row] = pv;
                ps += pv; pq += pv * pv;
            }
        }
        if (ln == 0) { redF[wv] = ps; redD[wv] = pq; }
        __syncthreads();
        if (tid == 0) {
            float a = 0.0f, b = 0.0f;
            #pragma unroll
            for (int i = 0; i < 8; ++i) { a += redF[i]; b += redD[i]; }
            atomicAdd(p.s3, a); atomicAdd(p.q3, b);
        }
    }

    // ---- scan: 20 steps, 2 grid syncs each ----
    for (int t = 0; t < TSTEPS; ++t) {
        // L1: h1 = xt @ W1t^T   (xt block-local -> no sync needed entering)
        preload_w<5>(p.W1b + (size_t)t * NPAD * DDIM, DDIM, rW, tid);
        #pragma unroll
        for (int j = 0; j < 5; ++j) acc[j] = (f32x4){0.f, 0.f, 0.f, 0.f};
        gemm_phase<4, 5, false>(p.W1b + (size_t)t * NPAD * DDIM, xbuf, As1, Bs,
                                sS, sT, acc, rW, tid);
        epi_store_stats(acc, p.b1p + t * NPAD, h1buf, redS, redQ,
                        p.csA + t * NPAD, p.cqA + t * NPAD, tid);
        preload_w<5>(p.W2b + (size_t)t * NPAD * NPAD, NPAD, rW, tid);
        grid.sync();

        // L2: h2 = bnrelu(h1) @ W2t^T
        bn_coeff(p.csA + t * NPAD, p.cqA + t * NPAD,
                 p.g1 + (size_t)t * HDIM, p.be1 + (size_t)t * HDIM, sS, sT, tid);
        #pragma unroll
        for (int j = 0; j < 5; ++j) acc[j] = (f32x4){0.f, 0.f, 0.f, 0.f};
        __syncthreads();
        gemm_phase<5, 5, true>(p.W2b + (size_t)t * NPAD * NPAD, h1buf, As1, Bs,
                               sS, sT, acc, rW, tid);
        epi_store_stats(acc, p.b2p + t * NPAD, h2buf, redS, redQ,
                        p.csB + t * NPAD, p.cqB + t * NPAD, tid);
        preload_w<4>(p.W3b + (size_t)t * DDIM * NPAD, NPAD, rW, tid);
        grid.sync();

        // L3: grad = bnrelu(h2) @ W3t^T + SDE update (block-local)
        bn_coeff(p.csB + t * NPAD, p.cqB + t * NPAD,
                 p.g2 + (size_t)t * HDIM, p.be2 + (size_t)t * HDIM, sS, sT, tid);
        #pragma unroll
        for (int j = 0; j < 4; ++j) acc[j] = (f32x4){0.f, 0.f, 0.f, 0.f};
        __syncthreads();
        gemm_phase<5, 4, true>(p.W3b + (size_t)t * DDIM * NPAD, h2buf, As1, Bs,
                               sS, sT, acc, rW, tid);

        const float ht = p.tg[t + 1] - p.tg[t];
        const float sn = sqrtf(ht);
        const float* xi_t = p.xi + (size_t)t * BATCH * DDIM;
        float fr[4] = {0.f, 0.f, 0.f, 0.f};
        float dr[4] = {0.f, 0.f, 0.f, 0.f};
        #pragma unroll
        for (int j = 0; j < 4; ++j) {
            const int col = ch * 64 + j * 16 + m;
            const float bv = p.b3[(size_t)t * DDIM + col];
            #pragma unroll
            for (int r = 0; r < 4; ++r) {
                const int lr = rh * 16 + q * 4 + r;
                const size_t idx = (size_t)(row0 + lr) * DDIM + col;
                float grad = acc[j][r] + bv;
                float noise = sn * xi_t[idx];
                const int xo = (ch * 32 + lr) * LSTR + (j * 16 + m);
                float nx = bf2f(xbuf[xo]) - grad * ht + noise;
                xbuf[xo] = f2bf(nx);
                if (t == TSTEPS - 1) p.xout[idx] = nx;
                fr[r] += grad * grad;
                dr[r] += grad * noise;
            }
        }
        #pragma unroll
        for (int r = 0; r < 4; ++r) {
            fr[r] += __shfl_xor(fr[r], 1); dr[r] += __shfl_xor(dr[r], 1);
            fr[r] += __shfl_xor(fr[r], 2); dr[r] += __shfl_xor(dr[r], 2);
            fr[r] += __shfl_xor(fr[r], 4); dr[r] += __shfl_xor(dr[r], 4);
            fr[r] += __shfl_xor(fr[r], 8); dr[r] += __shfl_xor(dr[r], 8);
        }
        if (m == 0) {
            #pragma unroll
            for (int r = 0; r < 4; ++r) {
                redF[ch * 32 + rh * 16 + q * 4 + r] = fr[r];
                redD[ch * 32 + rh * 16 + q * 4 + r] = dr[r];
            }
        }
        __syncthreads();
        if (tid < 32) {
            float fsum = redF[tid] + redF[32 + tid] + redF[64 + tid] + redF[96 + tid];
            float dsum = redD[tid] + redD[32 + tid] + redD[64 + tid] + redD[96 + tid];
            vacc[tid] += dsum - fsum * ht;
        }
        __syncthreads();
    }

    // ---- final vT (s3/q3 complete since long before: 40 grid syncs ago) ----
    if (tid < 32) {
        float mn = p.s3[0] * (1.0f / BATCH);
        float va = fmaxf(p.q3[0] * (1.0f / BATCH) - mn * mn, 0.0f);
        float rs = rsqrtf(va + BN_EPS);
        float v0 = fmaxf(p.vg3[0] * (pre3L[tid] - mn) * rs + p.vbe3[0], 0.0f);
        p.out[row0 + tid] = v0 + vacc[tid];
    }
}

extern "C" void kernel_launch(void* const* d_in, const int* in_sizes, int n_in,
                              void* d_out, int out_size, void* d_ws, size_t ws_size,
                              hipStream_t stream)
{
    const float* x    = (const float*)d_in[0];
    const float* xi   = (const float*)d_in[1];
    const float* tg   = (const float*)d_in[2];
    const float* W1   = (const float*)d_in[3];
    const float* b1   = (const float*)d_in[4];
    const float* g1   = (const float*)d_in[5];
    const float* be1  = (const float*)d_in[6];
    const float* W2   = (const float*)d_in[7];
    const float* b2   = (const float*)d_in[8];
    const float* g2   = (const float*)d_in[9];
    const float* be2  = (const float*)d_in[10];
    const float* W3   = (const float*)d_in[11];
    const float* b3   = (const float*)d_in[12];
    const float* vW1  = (const float*)d_in[13];
    const float* vb1  = (const float*)d_in[14];
    const float* vg1  = (const float*)d_in[15];
    const float* vbe1 = (const float*)d_in[16];
    const float* vW2  = (const float*)d_in[17];
    const float* vb2  = (const float*)d_in[18];
    const float* vg2  = (const float*)d_in[19];
    const float* vbe2 = (const float*)d_in[20];
    const float* vW3  = (const float*)d_in[21];
    const float* vb3  = (const float*)d_in[22];
    const float* vg3  = (const float*)d_in[23];
    const float* vbe3 = (const float*)d_in[24];

    float* out  = (float*)d_out;       // [0,B): vT ; [B, B+B*D): xT (fp32)
    float* xout = out + BATCH;

    // ---- workspace layout: weights (bf16), then fp32 biases + stats ----
    short* W1b  = (short*)d_ws;
    short* W2b  = W1b + SZ_W1B;
    short* W3b  = W2b + SZ_W2B;
    short* vW1b = W3b + SZ_W3B;
    short* vW2b = vW1b + SZ_VW1;
    float* b1p  = (float*)(vW2b + SZ_VW2);
    float* b2p  = b1p + TSTEPS * NPAD;
    float* vb1p = b2p + TSTEPS * NPAD;
    float* vb2p = vb1p + NPAD;
    float* vW3p = vb2p + NPAD;
    float* csA  = vW3p + NPAD;                 // zero region starts here
    float* cqA  = csA + 21 * NPAD;
    float* csB  = cqA + 21 * NPAD;
    float* cqB  = csB + 21 * NPAD;
    float* s3   = cqB + 21 * NPAD;
    float* q3   = s3 + 1;

    prep_k<<<dim3((int)((PREP_TOTAL + 255) / 256)), dim3(256), 0, stream>>>(
        W1b, W1, W2b, W2, W3b, W3, vW1b, vW1, vW2b, vW2,
        b1p, b1, b2p, b2, vb1p, vb1, vb2p, vb2, vW3p, vW3, csA);

    PArgs pa;
    pa.x = x; pa.xi = xi; pa.tg = tg;
    pa.W1b = W1b; pa.W2b = W2b; pa.W3b = W3b;
    pa.vW1b = vW1b; pa.vW2b = vW2b;
    pa.b1p = b1p; pa.b2p = b2p; pa.b3 = b3;
    pa.vb1p = vb1p; pa.vb2p = vb2p; pa.vW3p = vW3p; pa.vb3 = vb3;
    pa.g1 = g1; pa.be1 = be1; pa.g2 = g2; pa.be2 = be2;
    pa.vg1 = vg1; pa.vbe1 = vbe1; pa.vg2 = vg2; pa.vbe2 = vbe2;
    pa.vg3 = vg3; pa.vbe3 = vbe3;
    pa.csA = csA; pa.cqA = cqA; pa.csB = csB; pa.cqB = cqB;
    pa.s3 = s3; pa.q3 = q3;
    pa.out = out; pa.xout = xout;

    void* kargs[] = { (void*)&pa };
    hipLaunchCooperativeKernel((const void*)persist_k, dim3(BATCH / 32), dim3(512),
                               kargs, 0, stream);
}

// Round 3
// 1192.535 us; speedup vs baseline: 1.8012x; 1.8012x over previous
//
#include <hip/hip_runtime.h>
#include <hip/hip_bf16.h>
#include <math.h>

#define BATCH 8192
#define DDIM 256
#define HDIM 266
#define NPAD 320
#define TSTEPS 20
#define BN_EPS 1e-5f
#define LSTR 72         // LDS row stride in shorts (144 B; even bank spread for b128)
#define NBLK 256
#define NBAR 64

typedef __attribute__((ext_vector_type(8))) short short8;   // 8 bf16
typedef __attribute__((ext_vector_type(4))) float f32x4;

__device__ __forceinline__ short f2bf(float f) {
    __hip_bfloat16 h = __float2bfloat16(f);
    return *reinterpret_cast<short*>(&h);
}
__device__ __forceinline__ float bf2f(short s) {
    union { unsigned u; float f; } v;
    v.u = ((unsigned)(unsigned short)s) << 16;
    return v.f;
}

// ---------------------------------------------------------------------------
// prep: pad+convert all weights (bf16) / biases (fp32); zero stats + barriers.
// ---------------------------------------------------------------------------
#define SZ_W1B (20L * 320 * 256)
#define SZ_W2B (20L * 320 * 320)
#define SZ_W3B (20L * 256 * 320)
#define SZ_VW1 (320L * 256)
#define SZ_VW2 (320L * 320)
#define SZ_B1P (20L * 320)
#define SZ_B2P (20L * 320)
#define ZCOUNT (4L * 21 * NPAD + 2 + NBAR)
#define PREP_TOTAL (SZ_W1B + SZ_W2B + SZ_W3B + SZ_VW1 + SZ_VW2 + SZ_B1P + SZ_B2P + 3 * 320 + ZCOUNT)

__global__ __launch_bounds__(256)
void prep_k(short* __restrict__ W1b, const float* __restrict__ W1,
            short* __restrict__ W2b, const float* __restrict__ W2,
            short* __restrict__ W3b, const float* __restrict__ W3,
            short* __restrict__ vW1b, const float* __restrict__ vW1,
            short* __restrict__ vW2b, const float* __restrict__ vW2,
            float* __restrict__ b1p, const float* __restrict__ b1,
            float* __restrict__ b2p, const float* __restrict__ b2,
            float* __restrict__ vb1p, const float* __restrict__ vb1,
            float* __restrict__ vb2p, const float* __restrict__ vb2,
            float* __restrict__ vW3p, const float* __restrict__ vW3,
            float* __restrict__ zbase)
{
    long idx = (long)blockIdx.x * 256 + threadIdx.x;
    if (idx < SZ_W1B) {  // [20][320][256], src [20][266][256]
        long k = idx % 256, r = (idx / 256) % 320, t = idx / (256L * 320);
        float v = (r < HDIM) ? W1[((size_t)t * HDIM + r) * 256 + k] : 0.0f;
        W1b[idx] = f2bf(v); return;
    }
    idx -= SZ_W1B;
    if (idx < SZ_W2B) {  // [20][320][320], src [20][266][266]
        long k = idx % 320, r = (idx / 320) % 320, t = idx / (320L * 320);
        float v = (r < HDIM && k < HDIM) ? W2[((size_t)t * HDIM + r) * HDIM + k] : 0.0f;
        W2b[idx] = f2bf(v); return;
    }
    idx -= SZ_W2B;
    if (idx < SZ_W3B) {  // [20][256][320], src [20][256][266]
        long k = idx % 320, r = (idx / 320) % 256, t = idx / (320L * 256);
        float v = (k < HDIM) ? W3[((size_t)t * 256 + r) * HDIM + k] : 0.0f;
        W3b[idx] = f2bf(v); return;
    }
    idx -= SZ_W3B;
    if (idx < SZ_VW1) {  // [320][256], src [266][256]
        long k = idx % 256, r = idx / 256;
        float v = (r < HDIM) ? vW1[(size_t)r * 256 + k] : 0.0f;
        vW1b[idx] = f2bf(v); return;
    }
    idx -= SZ_VW1;
    if (idx < SZ_VW2) {  // [320][320], src [266][266]
        long k = idx % 320, r = idx / 320;
        float v = (r < HDIM && k < HDIM) ? vW2[(size_t)r * HDIM + k] : 0.0f;
        vW2b[idx] = f2bf(v); return;
    }
    idx -= SZ_VW2;
    if (idx < SZ_B1P) { long n = idx % 320, t = idx / 320;
        b1p[idx] = (n < HDIM) ? b1[(size_t)t * HDIM + n] : 0.0f; return; }
    idx -= SZ_B1P;
    if (idx < SZ_B2P) { long n = idx % 320, t = idx / 320;
        b2p[idx] = (n < HDIM) ? b2[(size_t)t * HDIM + n] : 0.0f; return; }
    idx -= SZ_B2P;
    if (idx < 320) { vb1p[idx] = (idx < HDIM) ? vb1[idx] : 0.0f; return; }
    idx -= 320;
    if (idx < 320) { vb2p[idx] = (idx < HDIM) ? vb2[idx] : 0.0f; return; }
    idx -= 320;
    if (idx < 320) { vW3p[idx] = (idx < HDIM) ? vW3[idx] : 0.0f; return; }
    idx -= 320;
    if (idx < ZCOUNT) { zbase[idx] = 0.0f; return; }
}

// ---------------------------------------------------------------------------
// Light grid barrier: all cross-block data travels via device-scope atomics
// (performed at the coherent point), so no L2 writeback/invalidate is needed —
// unlike cg::grid_group::sync() (~30 µs). Drain own memory ops, one arrival
// atomic per block, leader spins on an agent-scope load with s_sleep.
// ---------------------------------------------------------------------------
__device__ __forceinline__ void gridbar(unsigned* __restrict__ bar, int idx, int tid)
{
    asm volatile("s_waitcnt vmcnt(0) lgkmcnt(0)" ::: "memory");
    __syncthreads();   // every thread's atomics/stores are complete at L3
    if (tid == 0) {
        __hip_atomic_fetch_add(&bar[idx], 1u, __ATOMIC_RELAXED, __HIP_MEMORY_SCOPE_AGENT);
        while (__hip_atomic_load(&bar[idx], __ATOMIC_RELAXED, __HIP_MEMORY_SCOPE_AGENT)
               < (unsigned)NBLK) {
            __builtin_amdgcn_s_sleep(2);
        }
    }
    __syncthreads();
}

__device__ __forceinline__ float aload(const float* p)
{
    return __hip_atomic_load(p, __ATOMIC_RELAXED, __HIP_MEMORY_SCOPE_AGENT);
}

// BN coeffs from coherent (agent-scope) reads of the atomically-built stats.
__device__ __forceinline__ void bn_coeff(const float* __restrict__ cs,
                                         const float* __restrict__ cq,
                                         const float* __restrict__ g,
                                         const float* __restrict__ be,
                                         float* sS, float* sT, int tid)
{
    for (int k = tid; k < NPAD; k += 512) {
        float s = 0.0f, t = 0.0f;
        if (k < HDIM) {
            float mn = aload(&cs[k]) * (1.0f / BATCH);
            float vr = aload(&cq[k]) * (1.0f / BATCH) - mn * mn;
            float rs = rsqrtf(fmaxf(vr, 0.0f) + BN_EPS);
            s = g[k] * rs;
            t = be[k] - mn * s;
        }
        sS[k] = s; sT[k] = t;
    }
}

template<int NJ>
__device__ __forceinline__ void preload_w(const short* __restrict__ Wt, int KLEN,
                                          short8* rW, int tid)
{
    #pragma unroll
    for (int i = 0; i < NJ; ++i) {
        int s = tid + 512 * i;
        rW[i] = *(const short8*)(Wt + (size_t)(s >> 3) * KLEN + ((s & 7) * 8));
    }
}

// One GEMM phase: out 32 x (NJ*64), K = NKT*64.  A is chunk-major LDS
// ([chunk][32][LSTR]); if BN, A is re-normalized through As1 per chunk.
// rW must hold the chunk-0 weight tile (preloaded before the barrier).
template<int NKT, int NJ, bool BN>
__device__ __forceinline__ void gemm_phase(
    const short* __restrict__ Wt, const short* Asrc, short* As1, short* Bs,
    const float* sS, const float* sT, f32x4* acc, short8* rW, int tid)
{
    const int lane = tid & 63, q = lane >> 4, m = lane & 15;
    const int w = tid >> 6, rh = w >> 2, ch = w & 3;
    const int srowA = tid >> 3, kqA = (tid & 7) * 8;
    const int KLEN = NKT * 64;

    #pragma unroll
    for (int kt = 0; kt < NKT; ++kt) {
        if (BN) {
            if (tid < 256) {
                short8 v = *(const short8*)&Asrc[(kt * 32 + srowA) * LSTR + kqA];
                short8 ta;
                #pragma unroll
                for (int j = 0; j < 8; ++j) {
                    int k = kt * 64 + kqA + j;
                    float f = bf2f(v[j]);
                    f = fmaxf(f * sS[k] + sT[k], 0.0f);
                    ta[j] = f2bf(f);
                }
                *(short8*)&As1[srowA * LSTR + kqA] = ta;
            }
        }
        #pragma unroll
        for (int i = 0; i < NJ; ++i) {
            int s = tid + 512 * i;
            *(short8*)&Bs[(s >> 3) * LSTR + (s & 7) * 8] = rW[i];
        }
        __syncthreads();
        if (kt < NKT - 1) {
            #pragma unroll
            for (int i = 0; i < NJ; ++i) {
                int s = tid + 512 * i;
                rW[i] = *(const short8*)(Wt + (size_t)(s >> 3) * KLEN
                                         + (kt + 1) * 64 + ((s & 7) * 8));
            }
        }
        const short* ab = BN ? As1 : (Asrc + kt * 32 * LSTR);
        #pragma unroll
        for (int kk = 0; kk < 2; ++kk) {
            short8 fa = *(const short8*)&ab[(rh * 16 + m) * LSTR + kk * 32 + q * 8];
            #pragma unroll
            for (int j = 0; j < NJ; ++j) {
                short8 fb = *(const short8*)&Bs[(ch * (NJ * 16) + j * 16 + m) * LSTR
                                                + kk * 32 + q * 8];
                acc[j] = __builtin_amdgcn_mfma_f32_16x16x32_bf16(fa, fb, acc[j], 0, 0, 0);
            }
        }
        __syncthreads();
    }
}

// Epilogue for 320-wide phases: bias-add, store raw pre-BN h (chunk-major LDS),
// column sum/sumsq partials -> global atomics (cols < HDIM).
__device__ __forceinline__ void epi_store_stats(
    const f32x4* acc, const float* __restrict__ bias, short* dst,
    float* redS, float* redQ, float* __restrict__ csum, float* __restrict__ csq,
    int tid)
{
    const int lane = tid & 63, q = lane >> 4, m = lane & 15;
    const int w = tid >> 6, rh = w >> 2, ch = w & 3;
    float csv[5], cqv[5];
    #pragma unroll
    for (int j = 0; j < 5; ++j) {
        const int col = ch * 80 + j * 16 + m;
        const float bv = bias[col];
        float s = 0.0f, sq = 0.0f;
        #pragma unroll
        for (int r = 0; r < 4; ++r) {
            float v = acc[j][r] + bv;
            int row = rh * 16 + q * 4 + r;
            dst[((col >> 6) * 32 + row) * LSTR + (col & 63)] = f2bf(v);
            s += v; sq += v * v;
        }
        csv[j] = s; cqv[j] = sq;
    }
    #pragma unroll
    for (int j = 0; j < 5; ++j) {
        csv[j] += __shfl_xor(csv[j], 16); csv[j] += __shfl_xor(csv[j], 32);
        cqv[j] += __shfl_xor(cqv[j], 16); cqv[j] += __shfl_xor(cqv[j], 32);
    }
    if (q == 0) {
        #pragma unroll
        for (int j = 0; j < 5; ++j) {
            int col = ch * 80 + j * 16 + m;
            redS[rh * NPAD + col] = csv[j];
            redQ[rh * NPAD + col] = cqv[j];
        }
    }
    __syncthreads();
    if (tid < HDIM) {
        atomicAdd(&csum[tid], redS[tid] + redS[NPAD + tid]);
        atomicAdd(&csq[tid],  redQ[tid] + redQ[NPAD + tid]);
    }
}

struct PArgs {
    const float* x; const float* xi; const float* tg;
    const short* W1b; const short* W2b; const short* W3b;
    const short* vW1b; const short* vW2b;
    const float* b1p; const float* b2p; const float* b3;
    const float* vb1p; const float* vb2p; const float* vW3p; const float* vb3;
    const float* g1; const float* be1; const float* g2; const float* be2;
    const float* vg1; const float* vbe1; const float* vg2; const float* vbe2;
    const float* vg3; const float* vbe3;
    float* csA; float* cqA; float* csB; float* cqB;
    float* s3; float* q3;
    unsigned* bars;
    float* out; float* xout;
};

// ---------------------------------------------------------------------------
// Persistent kernel: 256 blocks x 512 threads, each block owns 32 rows for the
// whole v-net + 20-step scan. xt/h1/h2 live in LDS; cross-block data ONLY via
// device atomics; custom light barrier at the two BN points per step.
// ---------------------------------------------------------------------------
__global__ __launch_bounds__(512)
void persist_k(PArgs p)
{
    __shared__ __align__(16) short xbuf[128 * LSTR];    // xt  [4 chunks][32][LSTR]
    __shared__ __align__(16) short h1buf[160 * LSTR];   // h1  [5][32][LSTR] (pre-BN)
    __shared__ __align__(16) short h2buf[160 * LSTR];   // h2  [5][32][LSTR] (pre-BN)
    __shared__ __align__(16) short Bs[320 * LSTR];      // weight K-chunk
    __shared__ __align__(16) short As1[32 * LSTR];      // BN-staged A chunk
    __shared__ float sS[NPAD], sT[NPAD];
    __shared__ float redS[2 * NPAD], redQ[2 * NPAD];
    __shared__ float redF[128], redD[128];
    __shared__ float pre3L[32], vacc[32];

    const int tid = threadIdx.x;
    const int row0 = blockIdx.x * 32;
    const int lane = tid & 63, w = tid >> 6, q = lane >> 4, m = lane & 15;
    const int rh = w >> 2, ch = w & 3;
    int bidx = 0;

    // stage x -> xbuf (bf16, chunk-major); init per-row v accumulator
    for (int i2 = tid; i2 < 32 * 256; i2 += 512) {
        int row = i2 >> 8, col = i2 & 255;
        xbuf[((col >> 6) * 32 + row) * LSTR + (col & 63)] =
            f2bf(p.x[(size_t)(row0 + row) * DDIM + col]);
    }
    if (tid < 32) vacc[tid] = 0.0f;

    short8 rW[5];
    f32x4 acc[5];

    // ---- v-net layer 1: hv1 = x @ vW1^T ----
    preload_w<5>(p.vW1b, DDIM, rW, tid);
    #pragma unroll
    for (int j = 0; j < 5; ++j) acc[j] = (f32x4){0.f, 0.f, 0.f, 0.f};
    __syncthreads();
    gemm_phase<4, 5, false>(p.vW1b, xbuf, As1, Bs, sS, sT, acc, rW, tid);
    epi_store_stats(acc, p.vb1p, h1buf, redS, redQ,
                    p.csA + 20 * NPAD, p.cqA + 20 * NPAD, tid);
    preload_w<5>(p.vW2b, NPAD, rW, tid);
    gridbar(p.bars, bidx++, tid);

    // ---- v-net layer 2: hv2 = bnrelu(hv1) @ vW2^T ----
    bn_coeff(p.csA + 20 * NPAD, p.cqA + 20 * NPAD, p.vg1, p.vbe1, sS, sT, tid);
    #pragma unroll
    for (int j = 0; j < 5; ++j) acc[j] = (f32x4){0.f, 0.f, 0.f, 0.f};
    __syncthreads();
    gemm_phase<5, 5, true>(p.vW2b, h1buf, As1, Bs, sS, sT, acc, rW, tid);
    epi_store_stats(acc, p.vb2p, h2buf, redS, redQ,
                    p.csB + 20 * NPAD, p.cqB + 20 * NPAD, tid);
    gridbar(p.bars, bidx++, tid);

    // ---- v-net layer 3: pre3 = bnrelu(hv2) . vW3 (row dot, block-local) ----
    bn_coeff(p.csB + 20 * NPAD, p.cqB + 20 * NPAD, p.vg2, p.vbe2, sS, sT, tid);
    __syncthreads();
    {
        const int wv = tid >> 6, ln = tid & 63;
        float ps = 0.0f, pq = 0.0f;
        #pragma unroll
        for (int r4 = 0; r4 < 4; ++r4) {
            int row = wv * 4 + r4;
            float sum = 0.0f;
            #pragma unroll
            for (int c = 0; c < 5; ++c) {
                int k = c * 64 + ln;
                float v = fmaxf(bf2f(h2buf[(c * 32 + row) * LSTR + ln]) * sS[k] + sT[k], 0.0f);
                sum += v * p.vW3p[k];
            }
            sum += __shfl_xor(sum, 1);  sum += __shfl_xor(sum, 2);
            sum += __shfl_xor(sum, 4);  sum += __shfl_xor(sum, 8);
            sum += __shfl_xor(sum, 16); sum += __shfl_xor(sum, 32);
            if (ln == 0) {
                float pv = sum + p.vb3[0];
                pre3L[row] = pv;
                ps += pv; pq += pv * pv;
            }
        }
        if (ln == 0) { redF[wv] = ps; redD[wv] = pq; }
        __syncthreads();
        if (tid == 0) {
            float a = 0.0f, b = 0.0f;
            #pragma unroll
            for (int i = 0; i < 8; ++i) { a += redF[i]; b += redD[i]; }
            atomicAdd(p.s3, a); atomicAdd(p.q3, b);
        }
    }

    // ---- scan: 20 steps, 2 light barriers each ----
    for (int t = 0; t < TSTEPS; ++t) {
        // L1: h1 = xt @ W1t^T   (xt block-local -> no barrier needed entering)
        preload_w<5>(p.W1b + (size_t)t * NPAD * DDIM, DDIM, rW, tid);
        #pragma unroll
        for (int j = 0; j < 5; ++j) acc[j] = (f32x4){0.f, 0.f, 0.f, 0.f};
        gemm_phase<4, 5, false>(p.W1b + (size_t)t * NPAD * DDIM, xbuf, As1, Bs,
                                sS, sT, acc, rW, tid);
        epi_store_stats(acc, p.b1p + t * NPAD, h1buf, redS, redQ,
                        p.csA + t * NPAD, p.cqA + t * NPAD, tid);
        preload_w<5>(p.W2b + (size_t)t * NPAD * NPAD, NPAD, rW, tid);
        gridbar(p.bars, bidx++, tid);

        // L2: h2 = bnrelu(h1) @ W2t^T
        bn_coeff(p.csA + t * NPAD, p.cqA + t * NPAD,
                 p.g1 + (size_t)t * HDIM, p.be1 + (size_t)t * HDIM, sS, sT, tid);
        #pragma unroll
        for (int j = 0; j < 5; ++j) acc[j] = (f32x4){0.f, 0.f, 0.f, 0.f};
        __syncthreads();
        gemm_phase<5, 5, true>(p.W2b + (size_t)t * NPAD * NPAD, h1buf, As1, Bs,
                               sS, sT, acc, rW, tid);
        epi_store_stats(acc, p.b2p + t * NPAD, h2buf, redS, redQ,
                        p.csB + t * NPAD, p.cqB + t * NPAD, tid);
        preload_w<4>(p.W3b + (size_t)t * DDIM * NPAD, NPAD, rW, tid);
        gridbar(p.bars, bidx++, tid);

        // L3: grad = bnrelu(h2) @ W3t^T + SDE update (block-local)
        bn_coeff(p.csB + t * NPAD, p.cqB + t * NPAD,
                 p.g2 + (size_t)t * HDIM, p.be2 + (size_t)t * HDIM, sS, sT, tid);
        __syncthreads();

        // prefetch this step's xi fragment into registers (hides HBM latency
        // under the 5 MFMA chunks below)
        const float* xi_t = p.xi + (size_t)t * BATCH * DDIM;
        float xiv[16];
        #pragma unroll
        for (int j = 0; j < 4; ++j)
            #pragma unroll
            for (int r = 0; r < 4; ++r)
                xiv[j * 4 + r] = xi_t[(size_t)(row0 + rh * 16 + q * 4 + r) * DDIM
                                      + ch * 64 + j * 16 + m];

        #pragma unroll
        for (int j = 0; j < 4; ++j) acc[j] = (f32x4){0.f, 0.f, 0.f, 0.f};
        gemm_phase<5, 4, true>(p.W3b + (size_t)t * DDIM * NPAD, h2buf, As1, Bs,
                               sS, sT, acc, rW, tid);

        const float ht = p.tg[t + 1] - p.tg[t];
        const float sn = sqrtf(ht);
        float fr[4] = {0.f, 0.f, 0.f, 0.f};
        float dr[4] = {0.f, 0.f, 0.f, 0.f};
        #pragma unroll
        for (int j = 0; j < 4; ++j) {
            const int col = ch * 64 + j * 16 + m;
            const float bv = p.b3[(size_t)t * DDIM + col];
            #pragma unroll
            for (int r = 0; r < 4; ++r) {
                const int lr = rh * 16 + q * 4 + r;
                const size_t idx = (size_t)(row0 + lr) * DDIM + col;
                float grad = acc[j][r] + bv;
                float noise = sn * xiv[j * 4 + r];
                const int xo = (ch * 32 + lr) * LSTR + (j * 16 + m);
                float nx = bf2f(xbuf[xo]) - grad * ht + noise;
                xbuf[xo] = f2bf(nx);
                if (t == TSTEPS - 1) p.xout[idx] = nx;
                fr[r] += grad * grad;
                dr[r] += grad * noise;
            }
        }
        #pragma unroll
        for (int r = 0; r < 4; ++r) {
            fr[r] += __shfl_xor(fr[r], 1); dr[r] += __shfl_xor(dr[r], 1);
            fr[r] += __shfl_xor(fr[r], 2); dr[r] += __shfl_xor(dr[r], 2);
            fr[r] += __shfl_xor(fr[r], 4); dr[r] += __shfl_xor(dr[r], 4);
            fr[r] += __shfl_xor(fr[r], 8); dr[r] += __shfl_xor(dr[r], 8);
        }
        if (m == 0) {
            #pragma unroll
            for (int r = 0; r < 4; ++r) {
                redF[ch * 32 + rh * 16 + q * 4 + r] = fr[r];
                redD[ch * 32 + rh * 16 + q * 4 + r] = dr[r];
            }
        }
        __syncthreads();
        if (tid < 32) {
            float fsum = redF[tid] + redF[32 + tid] + redF[64 + tid] + redF[96 + tid];
            float dsum = redD[tid] + redD[32 + tid] + redD[64 + tid] + redD[96 + tid];
            vacc[tid] += dsum - fsum * ht;
        }
        __syncthreads();
    }

    // ---- final vT (s3/q3 complete: every block passed >=40 barriers since) ----
    if (tid < 32) {
        float mn = aload(p.s3) * (1.0f / BATCH);
        float va = fmaxf(aload(p.q3) * (1.0f / BATCH) - mn * mn, 0.0f);
        float rs = rsqrtf(va + BN_EPS);
        float v0 = fmaxf(p.vg3[0] * (pre3L[tid] - mn) * rs + p.vbe3[0], 0.0f);
        p.out[row0 + tid] = v0 + vacc[tid];
    }
}

extern "C" void kernel_launch(void* const* d_in, const int* in_sizes, int n_in,
                              void* d_out, int out_size, void* d_ws, size_t ws_size,
                              hipStream_t stream)
{
    const float* x    = (const float*)d_in[0];
    const float* xi   = (const float*)d_in[1];
    const float* tg   = (const float*)d_in[2];
    const float* W1   = (const float*)d_in[3];
    const float* b1   = (const float*)d_in[4];
    const float* g1   = (const float*)d_in[5];
    const float* be1  = (const float*)d_in[6];
    const float* W2   = (const float*)d_in[7];
    const float* b2   = (const float*)d_in[8];
    const float* g2   = (const float*)d_in[9];
    const float* be2  = (const float*)d_in[10];
    const float* W3   = (const float*)d_in[11];
    const float* b3   = (const float*)d_in[12];
    const float* vW1  = (const float*)d_in[13];
    const float* vb1  = (const float*)d_in[14];
    const float* vg1  = (const float*)d_in[15];
    const float* vbe1 = (const float*)d_in[16];
    const float* vW2  = (const float*)d_in[17];
    const float* vb2  = (const float*)d_in[18];
    const float* vg2  = (const float*)d_in[19];
    const float* vbe2 = (const float*)d_in[20];
    const float* vW3  = (const float*)d_in[21];
    const float* vb3  = (const float*)d_in[22];
    const float* vg3  = (const float*)d_in[23];
    const float* vbe3 = (const float*)d_in[24];

    float* out  = (float*)d_out;       // [0,B): vT ; [B, B+B*D): xT (fp32)
    float* xout = out + BATCH;

    // ---- workspace layout: weights (bf16), then fp32 biases + stats ----
    short* W1b  = (short*)d_ws;
    short* W2b  = W1b + SZ_W1B;
    short* W3b  = W2b + SZ_W2B;
    short* vW1b = W3b + SZ_W3B;
    short* vW2b = vW1b + SZ_VW1;
    float* b1p  = (float*)(vW2b + SZ_VW2);
    float* b2p  = b1p + TSTEPS * NPAD;
    float* vb1p = b2p + TSTEPS * NPAD;
    float* vb2p = vb1p + NPAD;
    float* vW3p = vb2p + NPAD;
    float* csA  = vW3p + NPAD;                 // zero region starts here
    float* cqA  = csA + 21 * NPAD;
    float* csB  = cqA + 21 * NPAD;
    float* cqB  = csB + 21 * NPAD;
    float* s3   = cqB + 21 * NPAD;
    float* q3   = s3 + 1;
    unsigned* bars = (unsigned*)(q3 + 1);      // NBAR counters, zeroed by prep

    prep_k<<<dim3((int)((PREP_TOTAL + 255) / 256)), dim3(256), 0, stream>>>(
        W1b, W1, W2b, W2, W3b, W3, vW1b, vW1, vW2b, vW2,
        b1p, b1, b2p, b2, vb1p, vb1, vb2p, vb2, vW3p, vW3, csA);

    PArgs pa;
    pa.x = x; pa.xi = xi; pa.tg = tg;
    pa.W1b = W1b; pa.W2b = W2b; pa.W3b = W3b;
    pa.vW1b = vW1b; pa.vW2b = vW2b;
    pa.b1p = b1p; pa.b2p = b2p; pa.b3 = b3;
    pa.vb1p = vb1p; pa.vb2p = vb2p; pa.vW3p = vW3p; pa.vb3 = vb3;
    pa.g1 = g1; pa.be1 = be1; pa.g2 = g2; pa.be2 = be2;
    pa.vg1 = vg1; pa.vbe1 = vbe1; pa.vg2 = vg2; pa.vbe2 = vbe2;
    pa.vg3 = vg3; pa.vbe3 = vbe3;
    pa.csA = csA; pa.cqA = cqA; pa.csB = csB; pa.cqB = cqB;
    pa.s3 = s3; pa.q3 = q3;
    pa.bars = bars;
    pa.out = out; pa.xout = xout;

    void* kargs[] = { (void*)&pa };
    hipLaunchCooperativeKernel((const void*)persist_k, dim3(NBLK), dim3(512),
                               kargs, 0, stream);
}